// Round 7
// baseline (469.676 us; speedup 1.0000x reference)
//
#include <hip/hip_runtime.h>
#include <math.h>

// (B,S,D,H,HD) = (2,2048,2048,16,128)
#define Bc   2
#define Sc   2048
#define Dc   2048
#define Hc   16
#define HDc  128
#define BSc  4096
#define HHDc 2048

typedef __bf16 bf16_t;
typedef __bf16 bf16x8 __attribute__((ext_vector_type(8)));
typedef __bf16 bf16x4 __attribute__((ext_vector_type(4)));
typedef float  f32x4  __attribute__((ext_vector_type(4)));

#define AS1(p) ((const __attribute__((address_space(1))) void*)(p))
#define AS3(p) ((__attribute__((address_space(3))) void*)(p))

#define MFMA16(a,b,c) __builtin_amdgcn_mfma_f32_16x16x32_bf16((a),(b),(c),0,0,0)

// ---------------------------------------------------------------------------
// x: fp32 -> bf16 (same layout)  [verified]
// ---------------------------------------------------------------------------
__global__ void convert_x(const float* __restrict__ x, bf16_t* __restrict__ xb)
{
    const size_t i = ((size_t)blockIdx.x * 256 + threadIdx.x) * 4;
    float4 v = *(const float4*)&x[i];
    bf16x4 o; o[0]=(bf16_t)v.x; o[1]=(bf16_t)v.y; o[2]=(bf16_t)v.z; o[3]=(bf16_t)v.w;
    *(bf16x4*)&xb[i] = o;
}

// ---------------------------------------------------------------------------
// W [K=2048][N=2048] fp32 -> W^T [N][K] bf16  [verified]
// ---------------------------------------------------------------------------
__global__ __launch_bounds__(256) void transpose_w(const float* __restrict__ in,
                                                   bf16_t* __restrict__ out)
{
    __shared__ float T[64][65];
    const int t = threadIdx.x;
    const int r0 = blockIdx.y * 64, c0 = blockIdx.x * 64;
    #pragma unroll
    for (int i = 0; i < 4; ++i) {
        int row = i * 16 + (t >> 4);
        int c4  = (t & 15) * 4;
        float4 v = *(const float4*)&in[(size_t)(r0 + row) * 2048 + c0 + c4];
        T[row][c4] = v.x; T[row][c4+1] = v.y; T[row][c4+2] = v.z; T[row][c4+3] = v.w;
    }
    __syncthreads();
    #pragma unroll
    for (int i = 0; i < 4; ++i) {
        int orow = i * 16 + (t >> 4);
        int c4   = (t & 15) * 4;
        bf16x4 o;
        #pragma unroll
        for (int j = 0; j < 4; ++j) o[j] = (bf16_t)T[c4 + j][orow];
        *(bf16x4*)&out[(size_t)(c0 + orow) * 2048 + r0 + c4] = o;
    }
}

// ---------------------------------------------------------------------------
// RoPE cos/sin table (values identical to old per-element path).
// ---------------------------------------------------------------------------
__global__ void rope_tab(float* __restrict__ tab)
{
    const int i = blockIdx.x * 256 + threadIdx.x;   // 131072 = s*64 + j
    const int j = i & 63, s = i >> 6;
    const float freq = expf(-(float)j * 0.14391156514261520f);
    float sn, cs;
    sincosf((float)s * freq, &sn, &cs);
    float2 v; v.x = cs; v.y = sn;
    *(float2*)&tab[i * 2] = v;
}

// ---------------------------------------------------------------------------
// mf_quad: 16 MFMA for one (M-sub, N-sub) quadrant of the wave's 128x64 tile.
// Template params keep all acc indices compile-time (rule #20).
// ---------------------------------------------------------------------------
template<int MS, int NS>
__device__ __forceinline__ void mf_quad(f32x4 (&acc)[8][4],
                                        const bf16x8 (&a)[4][2],
                                        const bf16x8 (&b)[2][2])
{
    #pragma unroll
    for (int ks = 0; ks < 2; ++ks)
        #pragma unroll
        for (int mf = 0; mf < 4; ++mf)
            #pragma unroll
            for (int nf = 0; nf < 2; ++nf)
                acc[MS * 4 + mf][NS * 2 + nf] =
                    MFMA16(a[mf][ks], b[nf][ks], acc[MS * 4 + mf][NS * 2 + nf]);
}

// ---------------------------------------------------------------------------
// qkv_gemm8: 256x256 tile, BK=64, 8 waves (2M x 4N), 8-phase schedule with
// counted vmcnt (T3+T4) + T2 swizzle + T5 setprio.  C[4096][6144] = xb*WT3^T.
//
// Half-tiles per K-tile (stage order A0,B0,B1,A1; 2 gload_lds/thread each):
//   A-half h = block rows {h*64..h*64+63} U {128+h*64..}  (each wave-M-half's
//              h-th 64 rows) ; B-half h = rows {q*64+h*32..+31, q=0..3}.
// Phase p of tile t (computing quadrant, staging tile t+1 into buf^1):
//   P1: vmcnt(4) bar | stage A0(t+1) | rd A-half0,B-half0 | mfma(0,0)
//   P2: vmcnt(4) bar | stage B0(t+1) | rd B-half1         | mfma(0,1)
//   P3: vmcnt(4) bar | stage B1(t+1) | rd A-half1,B-half0 | mfma(1,0)
//   P4:         bar  | stage A1(t+1) | rd B-half1         | mfma(1,1)
// Deadlines verified: P1 needs A0,B0 = oldest 4 of 8 outstanding -> vmcnt(4);
// P2 needs B1 (keep A1+A0' = 4); P3 needs A1 (keep A0'+B0' = 4); P4 none.
// Loads never drain to 0 in the main loop. Raw s_barrier + asm vmcnt
// ("memory" clobber orders LDS reads); stages always target the non-read
// buffer; the phase barrier orders last-reads before next-issue.
// Output router unchanged: Qf fp32 / Kf fp32 / Vt bf16 transposed.
// ---------------------------------------------------------------------------
__global__ __launch_bounds__(512, 2) void qkv_gemm8(const bf16_t* __restrict__ A,
                                                    const bf16_t* __restrict__ Bt,
                                                    float* __restrict__ Qf,
                                                    float* __restrict__ Kf,
                                                    bf16_t* __restrict__ Vt)
{
    __shared__ bf16_t As[2][256 * 64];   // 64 KiB
    __shared__ bf16_t Bs[2][256 * 64];   // 64 KiB

    const int t = threadIdx.x;
    const int w = t >> 6, l = t & 63;
    const int wm = w >> 2, wn = w & 3;
    const int lane15 = l & 15, quad = l >> 4;
    const int swr = (lane15 & 7) * 8;
    const int m0 = blockIdx.y * 256, n0 = blockIdx.x * 256;

    // staging constants: lane writes LDS chunk (l&7) of row (+l>>3); the
    // pre-swizzled global source chunk is (l&7)^((l>>3)&7)  [rule #21]
    const int gk = (((l & 7) ^ ((l >> 3) & 7)) * 8);

    auto stageA = [&](int buf, int h, int kt) {
        #pragma unroll
        for (int p = 0; p < 2; ++p) {
            const int rb = p * 128 + h * 64 + w * 8;      // wave-uniform
            __builtin_amdgcn_global_load_lds(
                AS1(A + (size_t)(m0 + rb + (l >> 3)) * 2048 + kt * 64 + gk),
                AS3(&As[buf][rb * 64]), 16, 0, 0);
        }
    };
    auto stageB = [&](int buf, int h, int kt) {
        #pragma unroll
        for (int p = 0; p < 2; ++p) {
            const int rb = (2 * p + (w >> 2)) * 64 + h * 32 + (w & 3) * 8;
            __builtin_amdgcn_global_load_lds(
                AS1(Bt + (size_t)(n0 + rb + (l >> 3)) * 2048 + kt * 64 + gk),
                AS3(&Bs[buf][rb * 64]), 16, 0, 0);
        }
    };

    bf16x8 a[4][2], b[2][2];
    auto rdA = [&](int buf, int msub) {
        #pragma unroll
        for (int mf = 0; mf < 4; ++mf)
            #pragma unroll
            for (int ks = 0; ks < 2; ++ks) {
                const int ra = wm * 128 + msub * 64 + mf * 16 + lane15;
                a[mf][ks] = *(const bf16x8*)&As[buf][ra * 64 + (((ks * 4 + quad) * 8) ^ swr)];
            }
    };
    auto rdB = [&](int buf, int nsub) {
        #pragma unroll
        for (int nf = 0; nf < 2; ++nf)
            #pragma unroll
            for (int ks = 0; ks < 2; ++ks) {
                const int rb = wn * 64 + nsub * 32 + nf * 16 + lane15;
                b[nf][ks] = *(const bf16x8*)&Bs[buf][rb * 64 + (((ks * 4 + quad) * 8) ^ swr)];
            }
    };

    f32x4 acc[8][4];
    #pragma unroll
    for (int i = 0; i < 8; ++i)
        #pragma unroll
        for (int j = 0; j < 4; ++j)
            #pragma unroll
            for (int c = 0; c < 4; ++c) acc[i][j][c] = 0.f;

    // prologue: tile 0 into buf0, stage order A0,B0,B1,A1 (8 loads in flight)
    stageA(0, 0, 0); stageB(0, 0, 0); stageB(0, 1, 0); stageA(0, 1, 0);

    for (int kt = 0; kt < 31; ++kt) {
        const int cur = kt & 1, nxt = cur ^ 1;
        // ---- P1 ----
        asm volatile("s_waitcnt vmcnt(4)" ::: "memory");
        __builtin_amdgcn_s_barrier();
        __builtin_amdgcn_sched_barrier(0);
        stageA(nxt, 0, kt + 1);
        rdA(cur, 0); rdB(cur, 0);
        __builtin_amdgcn_s_setprio(1); mf_quad<0,0>(acc, a, b); __builtin_amdgcn_s_setprio(0);
        // ---- P2 ----
        asm volatile("s_waitcnt vmcnt(4)" ::: "memory");
        __builtin_amdgcn_s_barrier();
        __builtin_amdgcn_sched_barrier(0);
        stageB(nxt, 0, kt + 1);
        rdB(cur, 1);
        __builtin_amdgcn_s_setprio(1); mf_quad<0,1>(acc, a, b); __builtin_amdgcn_s_setprio(0);
        // ---- P3 ----
        asm volatile("s_waitcnt vmcnt(4)" ::: "memory");
        __builtin_amdgcn_s_barrier();
        __builtin_amdgcn_sched_barrier(0);
        stageB(nxt, 1, kt + 1);
        rdA(cur, 1); rdB(cur, 0);
        __builtin_amdgcn_s_setprio(1); mf_quad<1,0>(acc, a, b); __builtin_amdgcn_s_setprio(0);
        // ---- P4 (no wait: B-half1(t) guaranteed since P2) ----
        __builtin_amdgcn_s_barrier();
        stageA(nxt, 1, kt + 1);
        rdB(cur, 1);
        __builtin_amdgcn_s_setprio(1); mf_quad<1,1>(acc, a, b); __builtin_amdgcn_s_setprio(0);
    }
    // ---- drain tile 31 (buf1): one full wait after a tile of cover ----
    asm volatile("s_waitcnt vmcnt(0)" ::: "memory");
    __builtin_amdgcn_s_barrier();
    __builtin_amdgcn_sched_barrier(0);
    rdA(1, 0); rdB(1, 0); mf_quad<0,0>(acc, a, b);
    rdB(1, 1);            mf_quad<0,1>(acc, a, b);
    rdA(1, 1); rdB(1, 0); mf_quad<1,0>(acc, a, b);
    rdB(1, 1);            mf_quad<1,1>(acc, a, b);

    // ---- epilogue: route Q (fp32) / K (fp32) / V (bf16 transposed) ----
    if (n0 < 4096) {
        float* __restrict__ dst = (n0 < 2048) ? Qf : Kf;
        const int nb = n0 & 2047;
        #pragma unroll
        for (int msub = 0; msub < 2; ++msub)
            #pragma unroll
            for (int mf = 0; mf < 4; ++mf)
                #pragma unroll
                for (int nsub = 0; nsub < 2; ++nsub)
                    #pragma unroll
                    for (int nf = 0; nf < 2; ++nf)
                        #pragma unroll
                        for (int r = 0; r < 4; ++r) {
                            const int gm = m0 + wm * 128 + msub * 64 + mf * 16 + quad * 4 + r;
                            const int gn = nb + wn * 64 + nsub * 32 + nf * 16 + lane15;
                            dst[(size_t)gm * 2048 + gn] = acc[msub * 4 + mf][nsub * 2 + nf][r];
                        }
    } else {
        const int nb = n0 - 4096;
        #pragma unroll
        for (int msub = 0; msub < 2; ++msub)
            #pragma unroll
            for (int mf = 0; mf < 4; ++mf) {
                const int gm = m0 + wm * 128 + msub * 64 + mf * 16 + quad * 4;  // +r
                const int bq = gm >> 11;
                const int s  = gm & 2047;
                #pragma unroll
                for (int nsub = 0; nsub < 2; ++nsub)
                    #pragma unroll
                    for (int nf = 0; nf < 2; ++nf) {
                        const int gn = nb + wn * 64 + nsub * 32 + nf * 16 + lane15;
                        const int h  = gn >> 7, hd = gn & 127;
                        bf16x4 o;
                        #pragma unroll
                        for (int r = 0; r < 4; ++r)
                            o[r] = (bf16_t)acc[msub * 4 + mf][nsub * 2 + nf][r];
                        *(bf16x4*)&Vt[((size_t)((bq * Hc + h) * HDc + hd)) * Sc + s] = o;
                    }
            }
    }
}

// ---------------------------------------------------------------------------
// GEMM: C[4096][2048] = A * Bt^T (final proj), 128^2 + T2 swizzle [verified]
// (256^2 grid would be only 128 blocks = half the CUs -> kept at 128^2.)
// ---------------------------------------------------------------------------
__global__ __launch_bounds__(256) void gemm_bt(const bf16_t* __restrict__ A,
                                               const bf16_t* __restrict__ Bt,
                                               float* __restrict__ C)
{
    __shared__ bf16_t As[128 * 64];
    __shared__ bf16_t Bs[128 * 64];
    const int t = threadIdx.x;
    const int w = t >> 6, l = t & 63;
    const int wm = w >> 1, wn = w & 1;
    const int lane15 = l & 15, quad = l >> 4;
    const int swr = (lane15 & 7) * 8;
    const int m0 = blockIdx.y * 128, n0 = blockIdx.x * 128;

    f32x4 acc[4][4];
    #pragma unroll
    for (int i = 0; i < 4; ++i)
        #pragma unroll
        for (int j = 0; j < 4; ++j)
            #pragma unroll
            for (int c = 0; c < 4; ++c) acc[i][j][c] = 0.f;

    const int srow = w * 8 + (l >> 3);
    const int gk   = ((l & 7) * 8) ^ ((srow & 7) * 8);

    for (int k0 = 0; k0 < 2048; k0 += 64) {
        __syncthreads();
        #pragma unroll
        for (int p = 0; p < 4; ++p) {
            __builtin_amdgcn_global_load_lds(
                AS1(A + (size_t)(m0 + p * 32 + srow) * 2048 + k0 + gk),
                AS3(&As[(p * 32 + w * 8) * 64]), 16, 0, 0);
            __builtin_amdgcn_global_load_lds(
                AS1(Bt + (size_t)(n0 + p * 32 + srow) * 2048 + k0 + gk),
                AS3(&Bs[(p * 32 + w * 8) * 64]), 16, 0, 0);
        }
        __syncthreads();
        #pragma unroll
        for (int ks = 0; ks < 2; ++ks) {
            const int rc = ((ks * 4 + quad) * 8) ^ swr;
            bf16x8 a[4], b[4];
            #pragma unroll
            for (int mt = 0; mt < 4; ++mt)
                a[mt] = *(const bf16x8*)&As[(wm * 64 + mt * 16 + lane15) * 64 + rc];
            #pragma unroll
            for (int nt = 0; nt < 4; ++nt)
                b[nt] = *(const bf16x8*)&Bs[(wn * 64 + nt * 16 + lane15) * 64 + rc];
            #pragma unroll
            for (int mt = 0; mt < 4; ++mt)
                #pragma unroll
                for (int nt = 0; nt < 4; ++nt)
                    acc[mt][nt] = MFMA16(a[mt], b[nt], acc[mt][nt]);
        }
    }

    #pragma unroll
    for (int mt = 0; mt < 4; ++mt)
        #pragma unroll
        for (int nt = 0; nt < 4; ++nt)
            #pragma unroll
            for (int r = 0; r < 4; ++r) {
                const int gm = m0 + wm * 64 + mt * 16 + quad * 4 + r;
                const int gn = n0 + wn * 64 + nt * 16 + lane15;
                C[(size_t)gm * 2048 + gn] = acc[mt][nt][r];
            }
}

// ---------------------------------------------------------------------------
// Fused RoPE + scale + bf16 cast, table-driven  [verified]
// ---------------------------------------------------------------------------
__global__ void rope_scale_cast(const float* __restrict__ Qf,
                                const float* __restrict__ Kf,
                                const float* __restrict__ tab,
                                bf16_t* __restrict__ Qh,
                                bf16_t* __restrict__ Kh)
{
    const int idx  = blockIdx.x * 256 + threadIdx.x;   // 1,048,576 total
    const int j4   = (idx & 15) * 4;                   // 0..60
    const int h    = (idx >> 4) & (Hc - 1);
    const int sabs = idx >> 8;
    const int s    = sabs & (Sc - 1);
    const float QS = 0.08838834764831845f;

    const size_t base = (size_t)sabs * HHDc + (size_t)h * HDc + j4;
    float4 q1 = *(const float4*)&Qf[base];
    float4 q2 = *(const float4*)&Qf[base + 64];
    float4 k1 = *(const float4*)&Kf[base];
    float4 k2 = *(const float4*)&Kf[base + 64];
    float4 t0 = *(const float4*)&tab[(s * 64 + j4) * 2];
    float4 t1 = *(const float4*)&tab[(s * 64 + j4 + 2) * 2];

    bf16x4 qo1, qo2, ko1, ko2;
    #pragma unroll
    for (int c = 0; c < 4; ++c) {
        const float cs = (c < 2) ? ((c & 1) ? t0.z : t0.x) : ((c & 1) ? t1.z : t1.x);
        const float sn = (c < 2) ? ((c & 1) ? t0.w : t0.y) : ((c & 1) ? t1.w : t1.y);
        const float a = ((const float*)&q1)[c], bq = ((const float*)&q2)[c];
        const float x = ((const float*)&k1)[c], y  = ((const float*)&k2)[c];
        qo1[c] = (bf16_t)((a * cs - bq * sn) * QS);
        qo2[c] = (bf16_t)((bq * cs + a * sn) * QS);
        ko1[c] = (bf16_t)(x * cs - y * sn);
        ko2[c] = (bf16_t)(y * cs + x * sn);
    }
    *(bf16x4*)&Qh[base]      = qo1;
    *(bf16x4*)&Qh[base + 64] = qo2;
    *(bf16x4*)&Kh[base]      = ko1;
    *(bf16x4*)&Kh[base + 64] = ko2;
}

// ---------------------------------------------------------------------------
// attn_v7 (R5-verified): swapped QK^T, lane-local softmax, reg-staged K/V.
// ---------------------------------------------------------------------------
__global__ __launch_bounds__(512, 4) void attn_v7(const bf16_t* __restrict__ Q,
                                                  const bf16_t* __restrict__ K,
                                                  const bf16_t* __restrict__ Vt,
                                                  bf16_t* __restrict__ CTX)
{
    __shared__ bf16_t Ks[64 * 128];    // [k_local][hd]   (col-swizzled)
    __shared__ bf16_t Vts[128 * 64];   // [hd][key_local] (col-swizzled)
    __shared__ bf16_t Ps[128 * 72];    // bf16 P[q][key], wave-private rows

    const int t = threadIdx.x, w = t >> 6, l = t & 63;
    const int lane15 = l & 15, quad = l >> 4;
    const int swr = (lane15 & 7) * 8;          // read-side column swizzle
    const int q0 = blockIdx.x * 128;
    const int b = blockIdx.y >> 4, h = blockIdx.y & 15;
    const size_t qbase = ((size_t)(b * Sc + q0)) * HHDc + h * HDc;
    const size_t vtb   = (size_t)blockIdx.y * HDc * Sc;
    const size_t kb0   = ((size_t)(b * Sc)) * HHDc + h * HDc;

    // ---- Q fragments straight to registers (wave owns 16 q-rows) ----
    bf16x8 qf[4];
    #pragma unroll
    for (int ks = 0; ks < 4; ++ks)
        qf[ks] = *(const bf16x8*)&Q[qbase
            + (size_t)(w * 16 + lane15) * HHDc + (ks * 4 + quad) * 8];

    // online-softmax state for q-row (w*16+lane15), replicated across quads
    float m_ = -INFINITY, l_ = 0.f;

    f32x4 O[8];        // PV acc: O[ht], hd=ht*16+quad*4+c, q=w*16+lane15
    #pragma unroll
    for (int i = 0; i < 8; ++i)
        #pragma unroll
        for (int c = 0; c < 4; ++c) O[i][c] = 0.f;

    // staging geometry (per thread)
    const int krow0 = w * 4 + (l >> 4);      // + p*32 ; K row (key index)
    const int kgc   = lane15 * 8;            // K global col (linear)
    const int vrow0 = w * 8 + (l >> 3);      // + p*64 ; Vt row (hd index)
    const int vgc   = (l & 7) * 8;           // Vt global col within tile

    bf16x8 kst[2], vst[2];
    // prologue: load tile 0 into registers
    #pragma unroll
    for (int p = 0; p < 2; ++p) {
        kst[p] = *(const bf16x8*)&K[kb0 + (size_t)(p * 32 + krow0) * HHDc + kgc];
        vst[p] = *(const bf16x8*)&Vt[vtb + (size_t)(p * 64 + vrow0) * Sc + vgc];
    }

    for (int kt = 0; kt < Sc / 64; ++kt) {
        __syncthreads();   // prev tile's readers done; Ks/Vts free
        // ---- write staged regs to LDS with swizzled column ----
        #pragma unroll
        for (int p = 0; p < 2; ++p) {
            const int rk = p * 32 + krow0;
            *(bf16x8*)&Ks[rk * 128 + (kgc ^ ((rk & 7) * 8))] = kst[p];
        }
        #pragma unroll
        for (int p = 0; p < 2; ++p) {
            const int rv = p * 64 + vrow0;
            *(bf16x8*)&Vts[rv * 64 + (vgc ^ ((rv & 7) * 8))] = vst[p];
        }
        // ---- issue next tile's global loads (hidden under compute) ----
        if (kt + 1 < Sc / 64) {
            const size_t kbn = kb0 + (size_t)(kt + 1) * 64 * HHDc;
            #pragma unroll
            for (int p = 0; p < 2; ++p) {
                kst[p] = *(const bf16x8*)&K[kbn + (size_t)(p * 32 + krow0) * HHDc + kgc];
                vst[p] = *(const bf16x8*)&Vt[vtb + (size_t)(p * 64 + vrow0) * Sc
                                             + (kt + 1) * 64 + vgc];
            }
        }
        __syncthreads();   // Ks/Vts ready for all waves

        // ---- swapped MFMA QK^T: sc[nt][r] = S[key=nt*16+quad*4+r][q=lane15] ----
        f32x4 sc[4];
        #pragma unroll
        for (int j = 0; j < 4; ++j)
            #pragma unroll
            for (int c = 0; c < 4; ++c) sc[j][c] = 0.f;
        __builtin_amdgcn_s_setprio(1);
        #pragma unroll
        for (int ks = 0; ks < 4; ++ks) {
            const int rc = ((ks * 4 + quad) * 8) ^ swr;   // swizzled column
            bf16x8 bk[4];
            #pragma unroll
            for (int nt = 0; nt < 4; ++nt)
                bk[nt] = *(const bf16x8*)&Ks[(nt * 16 + lane15) * 128 + rc];
            #pragma unroll
            for (int nt = 0; nt < 4; ++nt)
                sc[nt] = MFMA16(bk[nt], qf[ks], sc[nt]);   // A=K, B=Q
        }
        __builtin_amdgcn_s_setprio(0);

        // ---- in-register online softmax for q-row (w*16+lane15) ----
        {
            float tm = -INFINITY;
            #pragma unroll
            for (int nt = 0; nt < 4; ++nt)
                #pragma unroll
                for (int r = 0; r < 4; ++r) tm = fmaxf(tm, sc[nt][r]);
            tm = fmaxf(tm, __shfl_xor(tm, 16));
            tm = fmaxf(tm, __shfl_xor(tm, 32));
            const float mo = m_;
            const float mn = fmaxf(mo, tm);
            const float al = __expf(mo - mn);
            m_ = mn;
            float ts = 0.f;
            const int prow = (w * 16 + lane15) * 72;
            #pragma unroll
            for (int nt = 0; nt < 4; ++nt) {
                bf16x4 pw;
                #pragma unroll
                for (int r = 0; r < 4; ++r) {
                    const float p = __expf(sc[nt][r] - mn);
                    pw[r] = (bf16_t)p;
                    ts += p;
                }
                *(bf16x4*)&Ps[prow + nt * 16 + quad * 4] = pw;
            }
            ts += __shfl_xor(ts, 16);
            ts += __shfl_xor(ts, 32);
            l_ = l_ * al + ts;

            // ---- rescale O by lane-local alpha (O's q-index is lane15) ----
            #pragma unroll
            for (int ht = 0; ht < 8; ++ht)
                #pragma unroll
                for (int c = 0; c < 4; ++c) O[ht][c] *= al;
        }
        // Ps is wave-private: wave-synchronous exec + lgkmcnt ordering make a
        // block barrier unnecessary before the PV reads below.

        // ---- MFMA PV: ctx^T += V^T P^T ----
        __builtin_amdgcn_s_setprio(1);
        #pragma unroll
        for (int ks = 0; ks < 2; ++ks) {
            const int rcp = (ks * 4 + quad) * 8;          // Ps: NOT swizzled
            const int rcv = rcp ^ swr;                    // Vts: swizzled
            bf16x8 av[8];
            #pragma unroll
            for (int ht = 0; ht < 8; ++ht)
                av[ht] = *(const bf16x8*)&Vts[(ht * 16 + lane15) * 64 + rcv];
            bf16x8 bp = *(const bf16x8*)&Ps[(w * 16 + lane15) * 72 + rcp];
            #pragma unroll
            for (int ht = 0; ht < 8; ++ht)
                O[ht] = MFMA16(av[ht], bp, O[ht]);
        }
        __builtin_amdgcn_s_setprio(0);
    }

    // ---- write out (denominator is lane-local; no LDS, no barrier) ----
    {
        const float linv = 1.0f / l_;
        const int s = q0 + w * 16 + lane15;
        #pragma unroll
        for (int ht = 0; ht < 8; ++ht) {
            bf16x4 o;
            #pragma unroll
            for (int c = 0; c < 4; ++c) o[c] = (bf16_t)(O[ht][c] * linv);
            *(bf16x4*)&CTX[((size_t)(b * Sc + s)) * HHDc + h * HDc + ht * 16 + quad * 4] = o;
        }
    }
}

// ---------------------------------------------------------------------------
// ws layout (bf16 element offsets; total exactly 134,217,728 B):
//   xb  bf16 [0,        8388608)   -> Kh after qkv_gemm8 (xb dead)
//   WT3 bf16 [8388608,  20971520)  -> Qh after qkv_gemm8 (WT3 dead)
//   WoT bf16 [20971520, 25165824)  (alive until final gemm)
//   Qf  fp32 [25165824, 41943040)  -> CTX after rope_scale_cast (Qf dead)
//   Kf  fp32 [41943040, 58720256)
//   Vt  bf16 [58720256, 67108864)  (written transposed by qkv_gemm8)
// RoPE table (1 MB) lives in d_out, overwritten by the final gemm.
// ---------------------------------------------------------------------------
extern "C" void kernel_launch(void* const* d_in, const int* in_sizes, int n_in,
                              void* d_out, int out_size, void* d_ws, size_t ws_size,
                              hipStream_t stream)
{
    const float* x  = (const float*)d_in[0];
    const float* Wq = (const float*)d_in[2];
    const float* Wk = (const float*)d_in[3];
    const float* Wv = (const float*)d_in[4];
    const float* Wo = (const float*)d_in[5];
    float* out = (float*)d_out;

    bf16_t* W0  = (bf16_t*)d_ws;
    bf16_t* xb  = W0;
    bf16_t* WT3 = W0 + 8388608;
    bf16_t* WoT = W0 + 20971520;
    float*  Qf  = (float*)(W0 + 25165824);
    float*  Kf  = (float*)(W0 + 41943040);
    bf16_t* Vt  = W0 + 58720256;
    bf16_t* Kh  = W0;                     // alias: xb dead after qkv_gemm8
    bf16_t* Qh  = W0 + 8388608;           // alias: WT3 dead after qkv_gemm8
    bf16_t* CTX = W0 + 25165824;          // alias: Qf dead after rope_scale_cast
    float*  tab = out;                    // 1 MB table; out overwritten at end

    dim3 tw(32, 32);

    rope_tab<<<512, 256, 0, stream>>>(tab);
    convert_x<<<8192, 256, 0, stream>>>(x, xb);
    transpose_w<<<tw, 256, 0, stream>>>(Wq, WT3);
    transpose_w<<<tw, 256, 0, stream>>>(Wk, WT3 + 4194304);
    transpose_w<<<tw, 256, 0, stream>>>(Wv, WT3 + 8388608);
    transpose_w<<<tw, 256, 0, stream>>>(Wo, WoT);

    qkv_gemm8<<<dim3(24, 16), 512, 0, stream>>>(xb, WT3, Qf, Kf, Vt);

    rope_scale_cast<<<4096, 256, 0, stream>>>(Qf, Kf, tab, Qh, Kh);

    attn_v7<<<dim3(16, 32), 512, 0, stream>>>(Qh, Kh, Vt, CTX);

    gemm_bt<<<dim3(16, 32), 256, 0, stream>>>(CTX, WoT, out);
}

// Round 8
// 463.061 us; speedup vs baseline: 1.0143x; 1.0143x over previous
//
#include <hip/hip_runtime.h>
#include <math.h>

// (B,S,D,H,HD) = (2,2048,2048,16,128)
#define Bc   2
#define Sc   2048
#define Dc   2048
#define Hc   16
#define HDc  128
#define BSc  4096
#define HHDc 2048

typedef __bf16 bf16_t;
typedef __bf16 bf16x8 __attribute__((ext_vector_type(8)));
typedef __bf16 bf16x4 __attribute__((ext_vector_type(4)));
typedef float  f32x4  __attribute__((ext_vector_type(4)));

#define AS1(p) ((const __attribute__((address_space(1))) void*)(p))
#define AS3(p) ((__attribute__((address_space(3))) void*)(p))

#define MFMA16(a,b,c) __builtin_amdgcn_mfma_f32_16x16x32_bf16((a),(b),(c),0,0,0)

// ---------------------------------------------------------------------------
// x: fp32 -> bf16 (same layout)  [verified]
// ---------------------------------------------------------------------------
__global__ void convert_x(const float* __restrict__ x, bf16_t* __restrict__ xb)
{
    const size_t i = ((size_t)blockIdx.x * 256 + threadIdx.x) * 4;
    float4 v = *(const float4*)&x[i];
    bf16x4 o; o[0]=(bf16_t)v.x; o[1]=(bf16_t)v.y; o[2]=(bf16_t)v.z; o[3]=(bf16_t)v.w;
    *(bf16x4*)&xb[i] = o;
}

// ---------------------------------------------------------------------------
// W [K=2048][N=2048] fp32 -> W^T [N][K] bf16  [verified]
// ---------------------------------------------------------------------------
__global__ __launch_bounds__(256) void transpose_w(const float* __restrict__ in,
                                                   bf16_t* __restrict__ out)
{
    __shared__ float T[64][65];
    const int t = threadIdx.x;
    const int r0 = blockIdx.y * 64, c0 = blockIdx.x * 64;
    #pragma unroll
    for (int i = 0; i < 4; ++i) {
        int row = i * 16 + (t >> 4);
        int c4  = (t & 15) * 4;
        float4 v = *(const float4*)&in[(size_t)(r0 + row) * 2048 + c0 + c4];
        T[row][c4] = v.x; T[row][c4+1] = v.y; T[row][c4+2] = v.z; T[row][c4+3] = v.w;
    }
    __syncthreads();
    #pragma unroll
    for (int i = 0; i < 4; ++i) {
        int orow = i * 16 + (t >> 4);
        int c4   = (t & 15) * 4;
        bf16x4 o;
        #pragma unroll
        for (int j = 0; j < 4; ++j) o[j] = (bf16_t)T[c4 + j][orow];
        *(bf16x4*)&out[(size_t)(c0 + orow) * 2048 + r0 + c4] = o;
    }
}

// ---------------------------------------------------------------------------
// RoPE cos/sin table (values identical to old per-element path).
// ---------------------------------------------------------------------------
__global__ void rope_tab(float* __restrict__ tab)
{
    const int i = blockIdx.x * 256 + threadIdx.x;   // 131072 = s*64 + j
    const int j = i & 63, s = i >> 6;
    const float freq = expf(-(float)j * 0.14391156514261520f);
    float sn, cs;
    sincosf((float)s * freq, &sn, &cs);
    float2 v; v.x = cs; v.y = sn;
    *(float2*)&tab[i * 2] = v;
}

// ---------------------------------------------------------------------------
// Fused QKV GEMM + RoPE epilogue: C[4096][6144] = xb * WT3^T.
// Main loop = R6-verified 2-phase 128^2 with T2 swizzle (conflicts=0).
// Epilogue:
//   n0 >= 4096: V written bf16 TRANSPOSED [bh][hd][s]  (R6-verified).
//   n0 <  4096: a 128-wide n-block is exactly one head; rope pair (j,j+64)
//     spans the two wn-waves, so route acc fp32 through a 64x132 LDS tile
//     (union'd with staging bufs), pair in-LDS, apply table rope (+QS for Q),
//     store bf16 directly. Same fp32 values + same FMA order as the old
//     rope_scale_cast kernel -> bit-identical Qh/Kh.
// ---------------------------------------------------------------------------
union SMemQKV {
    struct { bf16_t As[128 * 64]; bf16_t Bs[128 * 64]; } g;   // 32 KB
    float T[64][132];                                          // 33.8 KB
};

__global__ __launch_bounds__(256) void qkv_gemm_rope(const bf16_t* __restrict__ A,
                                                     const bf16_t* __restrict__ Bt,
                                                     const float* __restrict__ tab,
                                                     bf16_t* __restrict__ Qh,
                                                     bf16_t* __restrict__ Kh,
                                                     bf16_t* __restrict__ Vt)
{
    __shared__ SMemQKV sm;
    const int t = threadIdx.x;
    const int w = t >> 6, l = t & 63;
    const int wm = w >> 1, wn = w & 1;
    const int lane15 = l & 15, quad = l >> 4;
    const int swr = (lane15 & 7) * 8;        // read-side column swizzle
    const int m0 = blockIdx.y * 128, n0 = blockIdx.x * 128;

    f32x4 acc[4][4];
    #pragma unroll
    for (int i = 0; i < 4; ++i)
        #pragma unroll
        for (int j = 0; j < 4; ++j)
            #pragma unroll
            for (int c = 0; c < 4; ++c) acc[i][j][c] = 0.f;

    const int srow = w * 8 + (l >> 3);
    const int gk   = ((l & 7) * 8) ^ ((srow & 7) * 8);   // inverse-swizzled src col

    for (int k0 = 0; k0 < 2048; k0 += 64) {
        __syncthreads();
        #pragma unroll
        for (int p = 0; p < 4; ++p) {
            __builtin_amdgcn_global_load_lds(
                AS1(A + (size_t)(m0 + p * 32 + srow) * 2048 + k0 + gk),
                AS3(&sm.g.As[(p * 32 + w * 8) * 64]), 16, 0, 0);
            __builtin_amdgcn_global_load_lds(
                AS1(Bt + (size_t)(n0 + p * 32 + srow) * 2048 + k0 + gk),
                AS3(&sm.g.Bs[(p * 32 + w * 8) * 64]), 16, 0, 0);
        }
        __syncthreads();
        #pragma unroll
        for (int ks = 0; ks < 2; ++ks) {
            const int rc = ((ks * 4 + quad) * 8) ^ swr;
            bf16x8 a[4], b[4];
            #pragma unroll
            for (int mt = 0; mt < 4; ++mt)
                a[mt] = *(const bf16x8*)&sm.g.As[(wm * 64 + mt * 16 + lane15) * 64 + rc];
            #pragma unroll
            for (int nt = 0; nt < 4; ++nt)
                b[nt] = *(const bf16x8*)&sm.g.Bs[(wn * 64 + nt * 16 + lane15) * 64 + rc];
            #pragma unroll
            for (int mt = 0; mt < 4; ++mt)
                #pragma unroll
                for (int nt = 0; nt < 4; ++nt)
                    acc[mt][nt] = MFMA16(a[mt], b[nt], acc[mt][nt]);
        }
    }

    if (n0 < 4096) {
        // ---- Q/K branch: rope + scale + bf16 cast via LDS pair exchange ----
        const bool isQ = (n0 < 2048);
        bf16_t* __restrict__ dst = isQ ? Qh : Kh;
        const float scale = isQ ? 0.08838834764831845f : 1.0f;
        const int h = (n0 & 2047) >> 7;          // block = exactly one head
        const int j4 = (t & 15) * 4;             // 0..60
        #pragma unroll
        for (int hp = 0; hp < 2; ++hp) {
            __syncthreads();                     // LDS free (K-loop / prev pass)
            if (wm == hp) {
                #pragma unroll
                for (int mt = 0; mt < 4; ++mt)
                    #pragma unroll
                    for (int nt = 0; nt < 4; ++nt)
                        #pragma unroll
                        for (int r = 0; r < 4; ++r)
                            sm.T[mt * 16 + quad * 4 + r][wn * 64 + nt * 16 + lane15]
                                = acc[mt][nt][r];
            }
            __syncthreads();
            #pragma unroll
            for (int rs = 0; rs < 4; ++rs) {
                const int lr = rs * 16 + (t >> 4);      // 0..63 local row
                const int gm = m0 + hp * 64 + lr;
                const int bq = gm >> 11, s = gm & 2047;
                float4 t0 = *(const float4*)&tab[(s * 64 + j4) * 2];
                float4 t1 = *(const float4*)&tab[(s * 64 + j4 + 2) * 2];
                bf16x4 o1, o2;
                #pragma unroll
                for (int c = 0; c < 4; ++c) {
                    const float cs = (c < 2) ? ((c & 1) ? t0.z : t0.x)
                                             : ((c & 1) ? t1.z : t1.x);
                    const float sn = (c < 2) ? ((c & 1) ? t0.w : t0.y)
                                             : ((c & 1) ? t1.w : t1.y);
                    const float a  = sm.T[lr][j4 + c];
                    const float bv = sm.T[lr][j4 + 64 + c];
                    o1[c] = (bf16_t)((a * cs - bv * sn) * scale);
                    o2[c] = (bf16_t)((bv * cs + a * sn) * scale);
                }
                const size_t ob = ((size_t)(bq * Sc + s)) * HHDc + h * HDc + j4;
                *(bf16x4*)&dst[ob]      = o1;
                *(bf16x4*)&dst[ob + 64] = o2;
            }
        }
    } else {
        // ---- V branch: write transposed Vt[bh][hd][s] (R6-verified) ----
        const int nb = n0 - 4096;
        #pragma unroll
        for (int mt = 0; mt < 4; ++mt) {
            const int gm = m0 + wm * 64 + mt * 16 + quad * 4;   // +r, 4 consec s
            const int bq = gm >> 11;
            const int s  = gm & 2047;
            #pragma unroll
            for (int nt = 0; nt < 4; ++nt) {
                const int gn = nb + wn * 64 + nt * 16 + lane15;
                const int h  = gn >> 7, hd = gn & 127;
                bf16x4 o;
                #pragma unroll
                for (int r = 0; r < 4; ++r) o[r] = (bf16_t)acc[mt][nt][r];
                *(bf16x4*)&Vt[((size_t)((bq * Hc + h) * HDc + hd)) * Sc + s] = o;
            }
        }
    }
}

// ---------------------------------------------------------------------------
// GEMM: C[4096][2048] = A * Bt^T (final proj), 128^2 + T2 swizzle [verified]
// ---------------------------------------------------------------------------
__global__ __launch_bounds__(256) void gemm_bt(const bf16_t* __restrict__ A,
                                               const bf16_t* __restrict__ Bt,
                                               float* __restrict__ C)
{
    __shared__ bf16_t As[128 * 64];
    __shared__ bf16_t Bs[128 * 64];
    const int t = threadIdx.x;
    const int w = t >> 6, l = t & 63;
    const int wm = w >> 1, wn = w & 1;
    const int lane15 = l & 15, quad = l >> 4;
    const int swr = (lane15 & 7) * 8;
    const int m0 = blockIdx.y * 128, n0 = blockIdx.x * 128;

    f32x4 acc[4][4];
    #pragma unroll
    for (int i = 0; i < 4; ++i)
        #pragma unroll
        for (int j = 0; j < 4; ++j)
            #pragma unroll
            for (int c = 0; c < 4; ++c) acc[i][j][c] = 0.f;

    const int srow = w * 8 + (l >> 3);
    const int gk   = ((l & 7) * 8) ^ ((srow & 7) * 8);

    for (int k0 = 0; k0 < 2048; k0 += 64) {
        __syncthreads();
        #pragma unroll
        for (int p = 0; p < 4; ++p) {
            __builtin_amdgcn_global_load_lds(
                AS1(A + (size_t)(m0 + p * 32 + srow) * 2048 + k0 + gk),
                AS3(&As[(p * 32 + w * 8) * 64]), 16, 0, 0);
            __builtin_amdgcn_global_load_lds(
                AS1(Bt + (size_t)(n0 + p * 32 + srow) * 2048 + k0 + gk),
                AS3(&Bs[(p * 32 + w * 8) * 64]), 16, 0, 0);
        }
        __syncthreads();
        #pragma unroll
        for (int ks = 0; ks < 2; ++ks) {
            const int rc = ((ks * 4 + quad) * 8) ^ swr;
            bf16x8 a[4], b[4];
            #pragma unroll
            for (int mt = 0; mt < 4; ++mt)
                a[mt] = *(const bf16x8*)&As[(wm * 64 + mt * 16 + lane15) * 64 + rc];
            #pragma unroll
            for (int nt = 0; nt < 4; ++nt)
                b[nt] = *(const bf16x8*)&Bs[(wn * 64 + nt * 16 + lane15) * 64 + rc];
            #pragma unroll
            for (int mt = 0; mt < 4; ++mt)
                #pragma unroll
                for (int nt = 0; nt < 4; ++nt)
                    acc[mt][nt] = MFMA16(a[mt], b[nt], acc[mt][nt]);
        }
    }

    #pragma unroll
    for (int mt = 0; mt < 4; ++mt)
        #pragma unroll
        for (int nt = 0; nt < 4; ++nt)
            #pragma unroll
            for (int r = 0; r < 4; ++r) {
                const int gm = m0 + wm * 64 + mt * 16 + quad * 4 + r;
                const int gn = n0 + wn * 64 + nt * 16 + lane15;
                C[(size_t)gm * 2048 + gn] = acc[mt][nt][r];
            }
}

// ---------------------------------------------------------------------------
// attn_v7 (R5-verified): swapped QK^T, lane-local softmax, reg-staged K/V.
// ---------------------------------------------------------------------------
__global__ __launch_bounds__(512, 4) void attn_v7(const bf16_t* __restrict__ Q,
                                                  const bf16_t* __restrict__ K,
                                                  const bf16_t* __restrict__ Vt,
                                                  bf16_t* __restrict__ CTX)
{
    __shared__ bf16_t Ks[64 * 128];    // [k_local][hd]   (col-swizzled)
    __shared__ bf16_t Vts[128 * 64];   // [hd][key_local] (col-swizzled)
    __shared__ bf16_t Ps[128 * 72];    // bf16 P[q][key], wave-private rows

    const int t = threadIdx.x, w = t >> 6, l = t & 63;
    const int lane15 = l & 15, quad = l >> 4;
    const int swr = (lane15 & 7) * 8;          // read-side column swizzle
    const int q0 = blockIdx.x * 128;
    const int b = blockIdx.y >> 4, h = blockIdx.y & 15;
    const size_t qbase = ((size_t)(b * Sc + q0)) * HHDc + h * HDc;
    const size_t vtb   = (size_t)blockIdx.y * HDc * Sc;
    const size_t kb0   = ((size_t)(b * Sc)) * HHDc + h * HDc;

    // ---- Q fragments straight to registers (wave owns 16 q-rows) ----
    bf16x8 qf[4];
    #pragma unroll
    for (int ks = 0; ks < 4; ++ks)
        qf[ks] = *(const bf16x8*)&Q[qbase
            + (size_t)(w * 16 + lane15) * HHDc + (ks * 4 + quad) * 8];

    // online-softmax state for q-row (w*16+lane15), replicated across quads
    float m_ = -INFINITY, l_ = 0.f;

    f32x4 O[8];        // PV acc: O[ht], hd=ht*16+quad*4+c, q=w*16+lane15
    #pragma unroll
    for (int i = 0; i < 8; ++i)
        #pragma unroll
        for (int c = 0; c < 4; ++c) O[i][c] = 0.f;

    // staging geometry (per thread)
    const int krow0 = w * 4 + (l >> 4);      // + p*32 ; K row (key index)
    const int kgc   = lane15 * 8;            // K global col (linear)
    const int vrow0 = w * 8 + (l >> 3);      // + p*64 ; Vt row (hd index)
    const int vgc   = (l & 7) * 8;           // Vt global col within tile

    bf16x8 kst[2], vst[2];
    // prologue: load tile 0 into registers
    #pragma unroll
    for (int p = 0; p < 2; ++p) {
        kst[p] = *(const bf16x8*)&K[kb0 + (size_t)(p * 32 + krow0) * HHDc + kgc];
        vst[p] = *(const bf16x8*)&Vt[vtb + (size_t)(p * 64 + vrow0) * Sc + vgc];
    }

    for (int kt = 0; kt < Sc / 64; ++kt) {
        __syncthreads();   // prev tile's readers done; Ks/Vts free
        // ---- write staged regs to LDS with swizzled column ----
        #pragma unroll
        for (int p = 0; p < 2; ++p) {
            const int rk = p * 32 + krow0;
            *(bf16x8*)&Ks[rk * 128 + (kgc ^ ((rk & 7) * 8))] = kst[p];
        }
        #pragma unroll
        for (int p = 0; p < 2; ++p) {
            const int rv = p * 64 + vrow0;
            *(bf16x8*)&Vts[rv * 64 + (vgc ^ ((rv & 7) * 8))] = vst[p];
        }
        // ---- issue next tile's global loads (hidden under compute) ----
        if (kt + 1 < Sc / 64) {
            const size_t kbn = kb0 + (size_t)(kt + 1) * 64 * HHDc;
            #pragma unroll
            for (int p = 0; p < 2; ++p) {
                kst[p] = *(const bf16x8*)&K[kbn + (size_t)(p * 32 + krow0) * HHDc + kgc];
                vst[p] = *(const bf16x8*)&Vt[vtb + (size_t)(p * 64 + vrow0) * Sc
                                             + (kt + 1) * 64 + vgc];
            }
        }
        __syncthreads();   // Ks/Vts ready for all waves

        // ---- swapped MFMA QK^T: sc[nt][r] = S[key=nt*16+quad*4+r][q=lane15] ----
        f32x4 sc[4];
        #pragma unroll
        for (int j = 0; j < 4; ++j)
            #pragma unroll
            for (int c = 0; c < 4; ++c) sc[j][c] = 0.f;
        __builtin_amdgcn_s_setprio(1);
        #pragma unroll
        for (int ks = 0; ks < 4; ++ks) {
            const int rc = ((ks * 4 + quad) * 8) ^ swr;   // swizzled column
            bf16x8 bk[4];
            #pragma unroll
            for (int nt = 0; nt < 4; ++nt)
                bk[nt] = *(const bf16x8*)&Ks[(nt * 16 + lane15) * 128 + rc];
            #pragma unroll
            for (int nt = 0; nt < 4; ++nt)
                sc[nt] = MFMA16(bk[nt], qf[ks], sc[nt]);   // A=K, B=Q
        }
        __builtin_amdgcn_s_setprio(0);

        // ---- in-register online softmax for q-row (w*16+lane15) ----
        {
            float tm = -INFINITY;
            #pragma unroll
            for (int nt = 0; nt < 4; ++nt)
                #pragma unroll
                for (int r = 0; r < 4; ++r) tm = fmaxf(tm, sc[nt][r]);
            tm = fmaxf(tm, __shfl_xor(tm, 16));
            tm = fmaxf(tm, __shfl_xor(tm, 32));
            const float mo = m_;
            const float mn = fmaxf(mo, tm);
            const float al = __expf(mo - mn);
            m_ = mn;
            float ts = 0.f;
            const int prow = (w * 16 + lane15) * 72;
            #pragma unroll
            for (int nt = 0; nt < 4; ++nt) {
                bf16x4 pw;
                #pragma unroll
                for (int r = 0; r < 4; ++r) {
                    const float p = __expf(sc[nt][r] - mn);
                    pw[r] = (bf16_t)p;
                    ts += p;
                }
                *(bf16x4*)&Ps[prow + nt * 16 + quad * 4] = pw;
            }
            ts += __shfl_xor(ts, 16);
            ts += __shfl_xor(ts, 32);
            l_ = l_ * al + ts;

            // ---- rescale O by lane-local alpha (O's q-index is lane15) ----
            #pragma unroll
            for (int ht = 0; ht < 8; ++ht)
                #pragma unroll
                for (int c = 0; c < 4; ++c) O[ht][c] *= al;
        }
        // Ps is wave-private: wave-synchronous exec + lgkmcnt ordering make a
        // block barrier unnecessary before the PV reads below.

        // ---- MFMA PV: ctx^T += V^T P^T ----
        __builtin_amdgcn_s_setprio(1);
        #pragma unroll
        for (int ks = 0; ks < 2; ++ks) {
            const int rcp = (ks * 4 + quad) * 8;          // Ps: NOT swizzled
            const int rcv = rcp ^ swr;                    // Vts: swizzled
            bf16x8 av[8];
            #pragma unroll
            for (int ht = 0; ht < 8; ++ht)
                av[ht] = *(const bf16x8*)&Vts[(ht * 16 + lane15) * 64 + rcv];
            bf16x8 bp = *(const bf16x8*)&Ps[(w * 16 + lane15) * 72 + rcp];
            #pragma unroll
            for (int ht = 0; ht < 8; ++ht)
                O[ht] = MFMA16(av[ht], bp, O[ht]);
        }
        __builtin_amdgcn_s_setprio(0);
    }

    // ---- write out (denominator is lane-local; no LDS, no barrier) ----
    {
        const float linv = 1.0f / l_;
        const int s = q0 + w * 16 + lane15;
        #pragma unroll
        for (int ht = 0; ht < 8; ++ht) {
            bf16x4 o;
            #pragma unroll
            for (int c = 0; c < 4; ++c) o[c] = (bf16_t)(O[ht][c] * linv);
            *(bf16x4*)&CTX[((size_t)(b * Sc + s)) * HHDc + h * HDc + ht * 16 + quad * 4] = o;
        }
    }
}

// ---------------------------------------------------------------------------
// ws layout (bf16 element offsets; total 117,440,512 B < 128 MB, NO aliasing):
//   xb  bf16 [0,        8388608)
//   WT3 bf16 [8388608,  20971520)
//   WoT bf16 [20971520, 25165824)
//   Qh  bf16 [25165824, 33554432)
//   Kh  bf16 [33554432, 41943040)
//   Vt  bf16 [41943040, 50331648)   (written transposed by qkv_gemm_rope)
//   CTX bf16 [50331648, 58720256)
// RoPE table (1 MB) lives in d_out; final gemm overwrites out at the end.
// ---------------------------------------------------------------------------
extern "C" void kernel_launch(void* const* d_in, const int* in_sizes, int n_in,
                              void* d_out, int out_size, void* d_ws, size_t ws_size,
                              hipStream_t stream)
{
    const float* x  = (const float*)d_in[0];
    const float* Wq = (const float*)d_in[2];
    const float* Wk = (const float*)d_in[3];
    const float* Wv = (const float*)d_in[4];
    const float* Wo = (const float*)d_in[5];
    float* out = (float*)d_out;

    bf16_t* W0  = (bf16_t*)d_ws;
    bf16_t* xb  = W0;
    bf16_t* WT3 = W0 + 8388608;
    bf16_t* WoT = W0 + 20971520;
    bf16_t* Qh  = W0 + 25165824;
    bf16_t* Kh  = W0 + 33554432;
    bf16_t* Vt  = W0 + 41943040;
    bf16_t* CTX = W0 + 50331648;
    float*  tab = out;                    // 1 MB table; out overwritten at end

    dim3 tw(32, 32);

    rope_tab<<<512, 256, 0, stream>>>(tab);
    convert_x<<<8192, 256, 0, stream>>>(x, xb);
    transpose_w<<<tw, 256, 0, stream>>>(Wq, WT3);
    transpose_w<<<tw, 256, 0, stream>>>(Wk, WT3 + 4194304);
    transpose_w<<<tw, 256, 0, stream>>>(Wv, WT3 + 8388608);
    transpose_w<<<tw, 256, 0, stream>>>(Wo, WoT);

    qkv_gemm_rope<<<dim3(48, 32), 256, 0, stream>>>(xb, WT3, tab, Qh, Kh, Vt);

    attn_v7<<<dim3(16, 32), 512, 0, stream>>>(Qh, Kh, Vt, CTX);

    gemm_bt<<<dim3(16, 32), 256, 0, stream>>>(CTX, WoT, out);
}

// Round 10
// 409.664 us; speedup vs baseline: 1.1465x; 1.1303x over previous
//
#include <hip/hip_runtime.h>
#include <math.h>

// (B,S,D,H,HD) = (2,2048,2048,16,128)
#define Bc   2
#define Sc   2048
#define Dc   2048
#define Hc   16
#define HDc  128
#define BSc  4096
#define HHDc 2048

typedef __bf16 bf16_t;
typedef __bf16 bf16x8 __attribute__((ext_vector_type(8)));
typedef __bf16 bf16x4 __attribute__((ext_vector_type(4)));
typedef float  f32x4  __attribute__((ext_vector_type(4)));

#define AS1(p) ((const __attribute__((address_space(1))) void*)(p))
#define AS3(p) ((__attribute__((address_space(3))) void*)(p))

#define MFMA16(a,b,c) __builtin_amdgcn_mfma_f32_16x16x32_bf16((a),(b),(c),0,0,0)

// ---------------------------------------------------------------------------
// x: fp32 -> bf16 (same layout)  [verified]
// ---------------------------------------------------------------------------
__global__ void convert_x(const float* __restrict__ x, bf16_t* __restrict__ xb)
{
    const size_t i = ((size_t)blockIdx.x * 256 + threadIdx.x) * 4;
    float4 v = *(const float4*)&x[i];
    bf16x4 o; o[0]=(bf16_t)v.x; o[1]=(bf16_t)v.y; o[2]=(bf16_t)v.z; o[3]=(bf16_t)v.w;
    *(bf16x4*)&xb[i] = o;
}

// ---------------------------------------------------------------------------
// W [K=2048][N=2048] fp32 -> W^T [N][K] bf16  [verified]
// ---------------------------------------------------------------------------
__global__ __launch_bounds__(256) void transpose_w(const float* __restrict__ in,
                                                   bf16_t* __restrict__ out)
{
    __shared__ float T[64][65];
    const int t = threadIdx.x;
    const int r0 = blockIdx.y * 64, c0 = blockIdx.x * 64;
    #pragma unroll
    for (int i = 0; i < 4; ++i) {
        int row = i * 16 + (t >> 4);
        int c4  = (t & 15) * 4;
        float4 v = *(const float4*)&in[(size_t)(r0 + row) * 2048 + c0 + c4];
        T[row][c4] = v.x; T[row][c4+1] = v.y; T[row][c4+2] = v.z; T[row][c4+3] = v.w;
    }
    __syncthreads();
    #pragma unroll
    for (int i = 0; i < 4; ++i) {
        int orow = i * 16 + (t >> 4);
        int c4   = (t & 15) * 4;
        bf16x4 o;
        #pragma unroll
        for (int j = 0; j < 4; ++j) o[j] = (bf16_t)T[c4 + j][orow];
        *(bf16x4*)&out[(size_t)(c0 + orow) * 2048 + r0 + c4] = o;
    }
}

// ---------------------------------------------------------------------------
// RoPE cos/sin table (values identical to old per-element path).
// ---------------------------------------------------------------------------
__global__ void rope_tab(float* __restrict__ tab)
{
    const int i = blockIdx.x * 256 + threadIdx.x;   // 131072 = s*64 + j
    const int j = i & 63, s = i >> 6;
    const float freq = expf(-(float)j * 0.14391156514261520f);
    float sn, cs;
    sincosf((float)s * freq, &sn, &cs);
    float2 v; v.x = cs; v.y = sn;
    *(float2*)&tab[i * 2] = v;
}

// ---------------------------------------------------------------------------
// Fused QKV GEMM + register-local RoPE epilogue. C[4096][6144] = xb * WT3^T.
// Main loop = R6-verified 2-phase 128^2 + T2 swizzle (conflicts=0).
//
// RoPE pairing trick: for Q/K n-blocks, the B-staging SOURCE row is permuted
// by the bit-permutation  hd(rh) = (rh&15)|((rh>>1)&0x30)|((rh&16)<<2)
// (rh bit4 <-> hd bit6; global_load_lds source addr is per-lane, LDS dest
// stays linear, T2 swizzle depends only on dest row -> unchanged).  Then
// acc col (wn,nt,lane15) holds q[j + (nt&1)*64], j = lane15 + (nt>>1)*16
// + wn*32, so the rope pair partner is acc[mt][nt^1][r] -- SAME THREAD.
// Epilogue: rope in fp32 on the exact acc values + store bf16 at the
// UNPERMUTED hd (j / j+64) -> Qh/Kh layout identical to R6; every value
// bit-identical to the verified R6 gemm+rope_scale_cast path.
//   n0 >= 4096: V written bf16 TRANSPOSED [bh][hd][s]  (R6-verified).
// ---------------------------------------------------------------------------
__global__ __launch_bounds__(256) void qkv_gemm_rope(const bf16_t* __restrict__ A,
                                                     const bf16_t* __restrict__ Bt,
                                                     const float* __restrict__ tab,
                                                     bf16_t* __restrict__ Qh,
                                                     bf16_t* __restrict__ Kh,
                                                     bf16_t* __restrict__ Vt)
{
    __shared__ bf16_t As[128 * 64];
    __shared__ bf16_t Bs[128 * 64];
    const int t = threadIdx.x;
    const int w = t >> 6, l = t & 63;
    const int wm = w >> 1, wn = w & 1;
    const int lane15 = l & 15, quad = l >> 4;
    const int swr = (lane15 & 7) * 8;        // read-side column swizzle
    const int m0 = blockIdx.y * 128, n0 = blockIdx.x * 128;
    const bool qk = (n0 < 4096);

    f32x4 acc[4][4];
    #pragma unroll
    for (int i = 0; i < 4; ++i)
        #pragma unroll
        for (int j = 0; j < 4; ++j)
            #pragma unroll
            for (int c = 0; c < 4; ++c) acc[i][j][c] = 0.f;

    const int srow = w * 8 + (l >> 3);
    const int gk   = ((l & 7) * 8) ^ ((srow & 7) * 8);   // inverse-swizzled src col

    // hoisted per-p staging bases (source row permuted for Q/K blocks)
    const bf16_t* Ap[4];
    const bf16_t* Bp[4];
    #pragma unroll
    for (int p = 0; p < 4; ++p) {
        Ap[p] = A + (size_t)(m0 + p * 32 + srow) * 2048 + gk;
        int gB = n0 + p * 32 + srow;
        if (qk) {
            const int rh = gB & 127;
            gB = (gB & ~127) | ((rh & 15) | ((rh >> 1) & 0x30) | ((rh & 16) << 2));
        }
        Bp[p] = Bt + (size_t)gB * 2048 + gk;
    }

    for (int k0 = 0; k0 < 2048; k0 += 64) {
        __syncthreads();
        #pragma unroll
        for (int p = 0; p < 4; ++p) {
            __builtin_amdgcn_global_load_lds(AS1(Ap[p] + k0),
                AS3(&As[(p * 32 + w * 8) * 64]), 16, 0, 0);
            __builtin_amdgcn_global_load_lds(AS1(Bp[p] + k0),
                AS3(&Bs[(p * 32 + w * 8) * 64]), 16, 0, 0);
        }
        __syncthreads();
        #pragma unroll
        for (int ks = 0; ks < 2; ++ks) {
            const int rc = ((ks * 4 + quad) * 8) ^ swr;
            bf16x8 a[4], b[4];
            #pragma unroll
            for (int mt = 0; mt < 4; ++mt)
                a[mt] = *(const bf16x8*)&As[(wm * 64 + mt * 16 + lane15) * 64 + rc];
            #pragma unroll
            for (int nt = 0; nt < 4; ++nt)
                b[nt] = *(const bf16x8*)&Bs[(wn * 64 + nt * 16 + lane15) * 64 + rc];
            #pragma unroll
            for (int mt = 0; mt < 4; ++mt)
                #pragma unroll
                for (int nt = 0; nt < 4; ++nt)
                    acc[mt][nt] = MFMA16(a[mt], b[nt], acc[mt][nt]);
        }
    }

    if (qk) {
        // ---- Q/K branch: register-local rope + scale + bf16 store ----
        const bool isQ = (n0 < 2048);
        bf16_t* __restrict__ dst = isQ ? Qh : Kh;
        const float QS = isQ ? 0.08838834764831845f : 1.0f;
        const int h = (n0 & 2047) >> 7;          // block = exactly one head
        #pragma unroll
        for (int mt = 0; mt < 4; ++mt)
            #pragma unroll
            for (int r = 0; r < 4; ++r) {
                const int gm = m0 + wm * 64 + mt * 16 + quad * 4 + r;
                const int bq = gm >> 11, spos = gm & 2047;
                const size_t ob = ((size_t)(bq * Sc + spos)) * HHDc + h * HDc;
                #pragma unroll
                for (int np = 0; np < 2; ++np) {     // pair (nt=2np, 2np+1)
                    const int j = lane15 + np * 16 + wn * 32;
                    const float2 cssn = *(const float2*)&tab[(spos * 64 + j) * 2];
                    const float v0 = acc[mt][2 * np][r];      // q[j]
                    const float v1 = acc[mt][2 * np + 1][r];  // q[j+64]
                    dst[ob + j]      = (bf16_t)((v0 * cssn.x - v1 * cssn.y) * QS);
                    dst[ob + j + 64] = (bf16_t)((v1 * cssn.x + v0 * cssn.y) * QS);
                }
            }
    } else {
        // ---- V branch: write transposed Vt[bh][hd][s] (R6-verified) ----
        const int nb = n0 - 4096;
        #pragma unroll
        for (int mt = 0; mt < 4; ++mt) {
            const int gm = m0 + wm * 64 + mt * 16 + quad * 4;   // +r, 4 consec s
            const int bq = gm >> 11;
            const int s  = gm & 2047;
            #pragma unroll
            for (int nt = 0; nt < 4; ++nt) {
                const int gn = nb + wn * 64 + nt * 16 + lane15;
                const int h  = gn >> 7, hd = gn & 127;
                bf16x4 o;
                #pragma unroll
                for (int r = 0; r < 4; ++r) o[r] = (bf16_t)acc[mt][nt][r];
                *(bf16x4*)&Vt[((size_t)((bq * Hc + h) * HDc + hd)) * Sc + s] = o;
            }
        }
    }
}

// ---------------------------------------------------------------------------
// GEMM: C[4096][2048] = A * Bt^T (final proj), 128^2 + T2 swizzle [verified]
// ---------------------------------------------------------------------------
__global__ __launch_bounds__(256) void gemm_bt(const bf16_t* __restrict__ A,
                                               const bf16_t* __restrict__ Bt,
                                               float* __restrict__ C)
{
    __shared__ bf16_t As[128 * 64];
    __shared__ bf16_t Bs[128 * 64];
    const int t = threadIdx.x;
    const int w = t >> 6, l = t & 63;
    const int wm = w >> 1, wn = w & 1;
    const int lane15 = l & 15, quad = l >> 4;
    const int swr = (lane15 & 7) * 8;
    const int m0 = blockIdx.y * 128, n0 = blockIdx.x * 128;

    f32x4 acc[4][4];
    #pragma unroll
    for (int i = 0; i < 4; ++i)
        #pragma unroll
        for (int j = 0; j < 4; ++j)
            #pragma unroll
            for (int c = 0; c < 4; ++c) acc[i][j][c] = 0.f;

    const int srow = w * 8 + (l >> 3);
    const int gk   = ((l & 7) * 8) ^ ((srow & 7) * 8);

    for (int k0 = 0; k0 < 2048; k0 += 64) {
        __syncthreads();
        #pragma unroll
        for (int p = 0; p < 4; ++p) {
            __builtin_amdgcn_global_load_lds(
                AS1(A + (size_t)(m0 + p * 32 + srow) * 2048 + k0 + gk),
                AS3(&As[(p * 32 + w * 8) * 64]), 16, 0, 0);
            __builtin_amdgcn_global_load_lds(
                AS1(Bt + (size_t)(n0 + p * 32 + srow) * 2048 + k0 + gk),
                AS3(&Bs[(p * 32 + w * 8) * 64]), 16, 0, 0);
        }
        __syncthreads();
        #pragma unroll
        for (int ks = 0; ks < 2; ++ks) {
            const int rc = ((ks * 4 + quad) * 8) ^ swr;
            bf16x8 a[4], b[4];
            #pragma unroll
            for (int mt = 0; mt < 4; ++mt)
                a[mt] = *(const bf16x8*)&As[(wm * 64 + mt * 16 + lane15) * 64 + rc];
            #pragma unroll
            for (int nt = 0; nt < 4; ++nt)
                b[nt] = *(const bf16x8*)&Bs[(wn * 64 + nt * 16 + lane15) * 64 + rc];
            #pragma unroll
            for (int mt = 0; mt < 4; ++mt)
                #pragma unroll
                for (int nt = 0; nt < 4; ++nt)
                    acc[mt][nt] = MFMA16(a[mt], b[nt], acc[mt][nt]);
        }
    }

    #pragma unroll
    for (int mt = 0; mt < 4; ++mt)
        #pragma unroll
        for (int nt = 0; nt < 4; ++nt)
            #pragma unroll
            for (int r = 0; r < 4; ++r) {
                const int gm = m0 + wm * 64 + mt * 16 + quad * 4 + r;
                const int gn = n0 + wn * 64 + nt * 16 + lane15;
                C[(size_t)gm * 2048 + gn] = acc[mt][nt][r];
            }
}

// ---------------------------------------------------------------------------
// attn_v7 (R5-verified): swapped QK^T, lane-local softmax, reg-staged K/V.
// ---------------------------------------------------------------------------
__global__ __launch_bounds__(512, 4) void attn_v7(const bf16_t* __restrict__ Q,
                                                  const bf16_t* __restrict__ K,
                                                  const bf16_t* __restrict__ Vt,
                                                  bf16_t* __restrict__ CTX)
{
    __shared__ bf16_t Ks[64 * 128];    // [k_local][hd]   (col-swizzled)
    __shared__ bf16_t Vts[128 * 64];   // [hd][key_local] (col-swizzled)
    __shared__ bf16_t Ps[128 * 72];    // bf16 P[q][key], wave-private rows

    const int t = threadIdx.x, w = t >> 6, l = t & 63;
    const int lane15 = l & 15, quad = l >> 4;
    const int swr = (lane15 & 7) * 8;          // read-side column swizzle
    const int q0 = blockIdx.x * 128;
    const int b = blockIdx.y >> 4, h = blockIdx.y & 15;
    const size_t qbase = ((size_t)(b * Sc + q0)) * HHDc + h * HDc;
    const size_t vtb   = (size_t)blockIdx.y * HDc * Sc;
    const size_t kb0   = ((size_t)(b * Sc)) * HHDc + h * HDc;

    // ---- Q fragments straight to registers (wave owns 16 q-rows) ----
    bf16x8 qf[4];
    #pragma unroll
    for (int ks = 0; ks < 4; ++ks)
        qf[ks] = *(const bf16x8*)&Q[qbase
            + (size_t)(w * 16 + lane15) * HHDc + (ks * 4 + quad) * 8];

    // online-softmax state for q-row (w*16+lane15), replicated across quads
    float m_ = -INFINITY, l_ = 0.f;

    f32x4 O[8];        // PV acc: O[ht], hd=ht*16+quad*4+c, q=w*16+lane15
    #pragma unroll
    for (int i = 0; i < 8; ++i)
        #pragma unroll
        for (int c = 0; c < 4; ++c) O[i][c] = 0.f;

    // staging geometry (per thread)
    const int krow0 = w * 4 + (l >> 4);      // + p*32 ; K row (key index)
    const int kgc   = lane15 * 8;            // K global col (linear)
    const int vrow0 = w * 8 + (l >> 3);      // + p*64 ; Vt row (hd index)
    const int vgc   = (l & 7) * 8;           // Vt global col within tile

    bf16x8 kst[2], vst[2];
    // prologue: load tile 0 into registers
    #pragma unroll
    for (int p = 0; p < 2; ++p) {
        kst[p] = *(const bf16x8*)&K[kb0 + (size_t)(p * 32 + krow0) * HHDc + kgc];
        vst[p] = *(const bf16x8*)&Vt[vtb + (size_t)(p * 64 + vrow0) * Sc + vgc];
    }

    for (int kt = 0; kt < Sc / 64; ++kt) {
        __syncthreads();   // prev tile's readers done; Ks/Vts free
        // ---- write staged regs to LDS with swizzled column ----
        #pragma unroll
        for (int p = 0; p < 2; ++p) {
            const int rk = p * 32 + krow0;
            *(bf16x8*)&Ks[rk * 128 + (kgc ^ ((rk & 7) * 8))] = kst[p];
        }
        #pragma unroll
        for (int p = 0; p < 2; ++p) {
            const int rv = p * 64 + vrow0;
            *(bf16x8*)&Vts[rv * 64 + (vgc ^ ((rv & 7) * 8))] = vst[p];
        }
        // ---- issue next tile's global loads (hidden under compute) ----
        if (kt + 1 < Sc / 64) {
            const size_t kbn = kb0 + (size_t)(kt + 1) * 64 * HHDc;
            #pragma unroll
            for (int p = 0; p < 2; ++p) {
                kst[p] = *(const bf16x8*)&K[kbn + (size_t)(p * 32 + krow0) * HHDc + kgc];
                vst[p] = *(const bf16x8*)&Vt[vtb + (size_t)(p * 64 + vrow0) * Sc
                                             + (kt + 1) * 64 + vgc];
            }
        }
        __syncthreads();   // Ks/Vts ready for all waves

        // ---- swapped MFMA QK^T: sc[nt][r] = S[key=nt*16+quad*4+r][q=lane15] ----
        f32x4 sc[4];
        #pragma unroll
        for (int j = 0; j < 4; ++j)
            #pragma unroll
            for (int c = 0; c < 4; ++c) sc[j][c] = 0.f;
        __builtin_amdgcn_s_setprio(1);
        #pragma unroll
        for (int ks = 0; ks < 4; ++ks) {
            const int rc = ((ks * 4 + quad) * 8) ^ swr;   // swizzled column
            bf16x8 bk[4];
            #pragma unroll
            for (int nt = 0; nt < 4; ++nt)
                bk[nt] = *(const bf16x8*)&Ks[(nt * 16 + lane15) * 128 + rc];
            #pragma unroll
            for (int nt = 0; nt < 4; ++nt)
                sc[nt] = MFMA16(bk[nt], qf[ks], sc[nt]);   // A=K, B=Q
        }
        __builtin_amdgcn_s_setprio(0);

        // ---- in-register online softmax for q-row (w*16+lane15) ----
        {
            float tm = -INFINITY;
            #pragma unroll
            for (int nt = 0; nt < 4; ++nt)
                #pragma unroll
                for (int r = 0; r < 4; ++r) tm = fmaxf(tm, sc[nt][r]);
            tm = fmaxf(tm, __shfl_xor(tm, 16));
            tm = fmaxf(tm, __shfl_xor(tm, 32));
            const float mo = m_;
            const float mn = fmaxf(mo, tm);
            const float al = __expf(mo - mn);
            m_ = mn;
            float ts = 0.f;
            const int prow = (w * 16 + lane15) * 72;
            #pragma unroll
            for (int nt = 0; nt < 4; ++nt) {
                bf16x4 pw;
                #pragma unroll
                for (int r = 0; r < 4; ++r) {
                    const float p = __expf(sc[nt][r] - mn);
                    pw[r] = (bf16_t)p;
                    ts += p;
                }
                *(bf16x4*)&Ps[prow + nt * 16 + quad * 4] = pw;
            }
            ts += __shfl_xor(ts, 16);
            ts += __shfl_xor(ts, 32);
            l_ = l_ * al + ts;

            // ---- rescale O by lane-local alpha (O's q-index is lane15) ----
            #pragma unroll
            for (int ht = 0; ht < 8; ++ht)
                #pragma unroll
                for (int c = 0; c < 4; ++c) O[ht][c] *= al;
        }
        // Ps is wave-private: wave-synchronous exec + lgkmcnt ordering make a
        // block barrier unnecessary before the PV reads below.

        // ---- MFMA PV: ctx^T += V^T P^T ----
        __builtin_amdgcn_s_setprio(1);
        #pragma unroll
        for (int ks = 0; ks < 2; ++ks) {
            const int rcp = (ks * 4 + quad) * 8;          // Ps: NOT swizzled
            const int rcv = rcp ^ swr;                    // Vts: swizzled
            bf16x8 av[8];
            #pragma unroll
            for (int ht = 0; ht < 8; ++ht)
                av[ht] = *(const bf16x8*)&Vts[(ht * 16 + lane15) * 64 + rcv];
            bf16x8 bp = *(const bf16x8*)&Ps[(w * 16 + lane15) * 72 + rcp];
            #pragma unroll
            for (int ht = 0; ht < 8; ++ht)
                O[ht] = MFMA16(av[ht], bp, O[ht]);
        }
        __builtin_amdgcn_s_setprio(0);
    }

    // ---- write out (denominator is lane-local; no LDS, no barrier) ----
    {
        const float linv = 1.0f / l_;
        const int s = q0 + w * 16 + lane15;
        #pragma unroll
        for (int ht = 0; ht < 8; ++ht) {
            bf16x4 o;
            #pragma unroll
            for (int c = 0; c < 4; ++c) o[c] = (bf16_t)(O[ht][c] * linv);
            *(bf16x4*)&CTX[((size_t)(b * Sc + s)) * HHDc + h * HDc + ht * 16 + quad * 4] = o;
        }
    }
}

// ---------------------------------------------------------------------------
// ws layout (bf16 element offsets; total 117,440,512 B < 128 MB, NO aliasing):
//   xb  bf16 [0,        8388608)
//   WT3 bf16 [8388608,  20971520)
//   WoT bf16 [20971520, 25165824)
//   Qh  bf16 [25165824, 33554432)
//   Kh  bf16 [33554432, 41943040)
//   Vt  bf16 [41943040, 50331648)   (written transposed by qkv_gemm_rope)
//   CTX bf16 [50331648, 58720256)
// RoPE table (1 MB) lives in d_out; final gemm overwrites out at the end.
// ---------------------------------------------------------------------------
extern "C" void kernel_launch(void* const* d_in, const int* in_sizes, int n_in,
                              void* d_out, int out_size, void* d_ws, size_t ws_size,
                              hipStream_t stream)
{
    const float* x  = (const float*)d_in[0];
    const float* Wq = (const float*)d_in[2];
    const float* Wk = (const float*)d_in[3];
    const float* Wv = (const float*)d_in[4];
    const float* Wo = (const float*)d_in[5];
    float* out = (float*)d_out;

    bf16_t* W0  = (bf16_t*)d_ws;
    bf16_t* xb  = W0;
    bf16_t* WT3 = W0 + 8388608;
    bf16_t* WoT = W0 + 20971520;
    bf16_t* Qh  = W0 + 25165824;
    bf16_t* Kh  = W0 + 33554432;
    bf16_t* Vt  = W0 + 41943040;
    bf16_t* CTX = W0 + 50331648;
    float*  tab = out;                    // 1 MB table; out overwritten at end

    dim3 tw(32, 32);

    rope_tab<<<512, 256, 0, stream>>>(tab);
    convert_x<<<8192, 256, 0, stream>>>(x, xb);
    transpose_w<<<tw, 256, 0, stream>>>(Wq, WT3);
    transpose_w<<<tw, 256, 0, stream>>>(Wk, WT3 + 4194304);
    transpose_w<<<tw, 256, 0, stream>>>(Wv, WT3 + 8388608);
    transpose_w<<<tw, 256, 0, stream>>>(Wo, WoT);

    qkv_gemm_rope<<<dim3(48, 32), 256, 0, stream>>>(xb, WT3, tab, Qh, Kh, Vt);

    attn_v7<<<dim3(16, 32), 512, 0, stream>>>(Qh, Kh, Vt, CTX);

    gemm_bt<<<dim3(16, 32), 256, 0, stream>>>(CTX, WoT, out);
}